// Round 8
// baseline (3114.171 us; speedup 1.0000x reference)
//
#include <hip/hip_runtime.h>
#include <hip/hip_bf16.h>

// MatchLSTM boundary-pointer model on MI355X (gfx950).
// B=32 T=400 J=30 V=50000 D=150 H=150 L=2. Output [B,2,401].
//
// Round 17 = round 16 (3090us; match_scan 1657us confirmed best) +
// off-match targets:
//  1) gru_scan: gi loads software-pipelined one step ahead (load t+1
//     during step t). R16 structure issued them at step top with only
//     phase A (~600cy) covering ~900cy HBM latency -> phase E stalled
//     on vmcnt every step. Now covered by a full step (~2000+cy).
//  2) zero_hr0 kernel folded into match_scan prologue (each (b,dir)
//     block zeroes its own Hr[b][0][dir*150..+150]); one less launch.
//  match_scan itself unchanged from R16 (1657us, FETCH/WRITE 33.7/15.0,
//  wave_sum64 kept).

namespace {

constexpr int NBATCH = 32;
constexpr int TLEN   = 400;
constexpr int JQ     = 30;
constexpr int T1     = 401;

__device__ __forceinline__ float sigm(float x){ return 1.f/(1.f+__expf(-x)); }
__device__ __forceinline__ float tanh_f(float x){
  float e = __expf(-2.f*fabsf(x));
  float t = (1.f-e)/(1.f+e);
  return x < 0.f ? -t : t;
}
__device__ __forceinline__ float bf2f(unsigned short u){
  union { unsigned int i; float f; } c; c.i = ((unsigned int)u)<<16; return c.f;
}
__device__ __forceinline__ float q4max(float4 v){ return fmaxf(fmaxf(v.x,v.y),fmaxf(v.z,v.w)); }
__device__ __forceinline__ float sum4(float4 v){ return (v.x+v.y)+(v.z+v.w); }
__device__ __forceinline__ float4 exp4(float4 v, float m){
  return make_float4(__expf(v.x-m),__expf(v.y-m),__expf(v.z-m),__expf(v.w-m));
}
__device__ __forceinline__ float4 scl4(float4 v, float s){
  return make_float4(v.x*s,v.y*s,v.z*s,v.w*s);
}

// Wave-64 sum with 1 DS op (vs 6 bpermutes): permlane32_swap (VALU) +
// ds_swizzle xor16 (DS) + DPP row_shr 8/4/2/1 adds (VALU). Total lands
// in lane 0 (also lanes 16/32/48).
__device__ __forceinline__ float wave_sum64(float a){
  float x = a, y = a;
  asm volatile("v_permlane32_swap_b32 %0, %1" : "+v"(x), "+v"(y));
  a = x + y;                                   // all lanes: lo+hi pair sum
  a += __int_as_float(__builtin_amdgcn_ds_swizzle(__float_as_int(a), 0x401F)); // ^16
  a += __int_as_float(__builtin_amdgcn_update_dpp(0, __float_as_int(a), 0x118, 0xF, 0xF, true));
  a += __int_as_float(__builtin_amdgcn_update_dpp(0, __float_as_int(a), 0x114, 0xF, 0xF, true));
  a += __int_as_float(__builtin_amdgcn_update_dpp(0, __float_as_int(a), 0x112, 0xF, 0xF, true));
  a += __int_as_float(__builtin_amdgcn_update_dpp(0, __float_as_int(a), 0x111, 0xF, 0xF, true));
  return a;
}

// LDS-only barrier: orders LDS producer->consumer across waves without
// draining vmcnt (global prefetch loads / stores stay in flight).
__device__ __forceinline__ void bar_lds(){
  asm volatile("s_waitcnt lgkmcnt(0)" ::: "memory");
  __builtin_amdgcn_s_barrier();
}

#define NW 29
struct WDesc { const void* src[NW]; int off[NW+1]; };

__global__ void sniff_kernel(const unsigned int* __restrict__ bits, int* __restrict__ flag){
  __shared__ int cnt;
  if (threadIdx.x==0) cnt = 0;
  __syncthreads();
  int hit = 0;
  #pragma unroll
  for (int i=0;i<4;i++){
    unsigned int w = bits[threadIdx.x*4+i];
    unsigned int b = (w>>8)&0x7Fu;
    if (b==0u || (b>=0x38u && b<=0x3Fu)) hit++;
  }
  atomicAdd(&cnt, hit);
  __syncthreads();
  if (threadIdx.x==0) *flag = (cnt > 768) ? 1 : 0;
}

__global__ void convert_weights_kernel(WDesc d, float* __restrict__ out, const int* __restrict__ flag){
  const int isbf = *flag;
  const int total = d.off[NW];
  for (int e = blockIdx.x*blockDim.x+threadIdx.x; e < total; e += gridDim.x*blockDim.x){
    int j = 0;
    while (e >= d.off[j+1]) j++;
    int i = e - d.off[j];
    out[e] = isbf ? bf2f(((const unsigned short*)d.src[j])[i])
                  : ((const float*)d.src[j])[i];
  }
}

// ---- fused weight-restructure kernel ----------
struct PrepArgs {
  const float *ctxWhh, *qWhh, *mWhh, *mrWhh, *Wr;
  const float *ctxWih, *qWih, *mWih, *mrWih;
  float *ctxWhhP, *qWhhP, *s2qCtx, *s2qQ, *WcatF, *WcatR, *s2qF, *s2qR;
  float *extF, *extR, *ctxWihT, *qWihT, *mXfT, *mXrT, *mQfT, *mQrT;
};

__global__ void prep_all_kernel(PrepArgs a){
  const int PN[16] = {68400,68400,21696,21696,91200,91200,24576,24576,
                      13376,13376,67500,67500,67500,67500,67500,67500};
  const int TOT = 843496;
  for (int gid = blockIdx.x*blockDim.x+threadIdx.x; gid < TOT; gid += gridDim.x*blockDim.x){
    int e = gid, t = 0;
    while (e >= PN[t]){ e -= PN[t]; t++; }
    switch (t){
      case 0: case 1: {                       // padrows Whh -> [450][152]
        const float* s = (t==0)? a.ctxWhh : a.qWhh;
        float* d = (t==0)? a.ctxWhhP : a.qWhhP;
        int r = e/152, c = e-r*152;
        d[e] = (c<150) ? s[r*150+c] : 0.f;
      } break;
      case 2: case 3: {                       // gsplit: [12][452] f4
        const float* s = (t==2)? a.ctxWhh : a.qWhh;
        float* d = (t==2)? a.s2qCtx : a.s2qQ;
        int q = e/1808, rem = e-q*1808, r = rem/4, p = rem-r*4;
        int c = 104 + 4*q + p;
        d[e] = (r<450 && c<150) ? s[(size_t)r*150+c] : 0.f;
      } break;
      case 4: case 5: {                       // Wcat [600][152]
        const float* s = (t==4)? a.mWhh : a.mrWhh;
        float* d = (t==4)? a.WcatF : a.WcatR;
        int r = e/152, c = e-r*152;
        float v = 0.f;
        if (c < 150) v = (r<450) ? s[(size_t)r*150+c] : a.Wr[(size_t)c*150 + (r-450)];
        d[e] = v;
      } break;
      case 6: case 7: {                       // msplit s2q [12][512] f4
        const float* s = (t==6)? a.mWhh : a.mrWhh;
        float* d = (t==6)? a.s2qF : a.s2qR;
        int q = e/2048, rem = e-q*2048, r = rem/4, p = rem-r*4;
        int c = 104 + 4*q + p;
        float v = 0.f;
        if (c < 150) v = (r<450) ? s[(size_t)r*150+c] : a.Wr[(size_t)c*150 + (r-450)];
        d[e] = v;
      } break;
      case 8: case 9: {                       // ext [38][88] f4 (Wr rows 512..599)
        float* d = (t==8)? a.extF : a.extR;
        int q = e/352, rem = e-q*352, ii = rem/4, p = rem-ii*4;
        int c = 4*q + p;
        d[e] = (c<150) ? a.Wr[(size_t)c*150 + 62 + ii] : 0.f;
      } break;
      default: {                              // transposes [150][450]
        int i2 = e/450, k = e-i2*450;
        const float* s; float* d; int lds_, offs;
        switch (t){
          case 10: s=a.ctxWih; d=a.ctxWihT; lds_=150; offs=0;   break;
          case 11: s=a.qWih;   d=a.qWihT;   lds_=150; offs=0;   break;
          case 12: s=a.mWih;   d=a.mXfT;    lds_=300; offs=0;   break;
          case 13: s=a.mrWih;  d=a.mXrT;    lds_=300; offs=0;   break;
          case 14: s=a.mWih;   d=a.mQfT;    lds_=300; offs=150; break;
          default: s=a.mrWih;  d=a.mQrT;    lds_=300; offs=150; break;
        }
        d[(size_t)i2*450 + k] = s[(size_t)k*lds_ + offs + i2];
      } break;
    }
  }
}

// ---- 16-row mode-0 projection: out[r,k] = bias[k] + sum_i x[r,i]*W[i*ldw+k]
__global__ __launch_bounds__(512) void rowproj16_kernel(
    const float* __restrict__ Xrows,
    const int* __restrict__ gather, const void* __restrict__ Etab, const int* __restrict__ bfflag,
    const float* __restrict__ W, const float* __restrict__ bias,
    float* __restrict__ out, int rows, int K, int inner, int ldw, int ldo)
{
  __shared__ __align__(16) float xs[16][304];
  const int r0 = blockIdx.x*16;
  int nr = rows - r0; if (nr > 16) nr = 16;
  if (nr <= 0) return;
  const int isbf = gather ? *bfflag : 0;
  for (int e = threadIdx.x; e < nr*inner; e += 512){
    int r = e/inner, i = e - r*inner;
    float v;
    if (gather){
      size_t base = (size_t)gather[r0+r]*inner + i;
      v = isbf ? bf2f(((const unsigned short*)Etab)[base]) : ((const float*)Etab)[base];
    } else {
      v = Xrows[(size_t)(r0+r)*inner + i];
    }
    xs[r][i] = v;
  }
  __syncthreads();
  for (int k = threadIdx.x; k < K; k += 512){
    float b0 = bias ? bias[k] : 0.f;
    float acc[16];
    #pragma unroll
    for (int r=0;r<16;r++) acc[r] = b0;
    int i = 0;
    for (; i+4 <= inner; i += 4){
      float w0 = W[(size_t)i*ldw + k];
      float w1 = W[(size_t)(i+1)*ldw + k];
      float w2 = W[(size_t)(i+2)*ldw + k];
      float w3 = W[(size_t)(i+3)*ldw + k];
      #pragma unroll
      for (int r=0;r<16;r++){
        float4 xv = *(const float4*)&xs[r][i];
        acc[r] = fmaf(xv.x, w0, acc[r]);
        acc[r] = fmaf(xv.y, w1, acc[r]);
        acc[r] = fmaf(xv.z, w2, acc[r]);
        acc[r] = fmaf(xv.w, w3, acc[r]);
      }
    }
    for (; i < inner; i++){
      float wv = W[(size_t)i*ldw + k];
      #pragma unroll
      for (int r=0;r<16;r++) acc[r] = fmaf(xs[r][i], wv, acc[r]);
    }
    for (int r=0;r<nr;r++) out[(size_t)(r0+r)*ldo + k] = acc[r];
  }
  for (int k = K + threadIdx.x; k < ldo; k += 512)
    for (int r=0;r<nr;r++) out[(size_t)(r0+r)*ldo + k] = 0.f;
}

// ---- triple rowproj sharing one staged X tile (inner=150 fixed) -----------
__device__ __forceinline__ void rowproj_one(
    const float xs[16][152], int nr, int r0,
    const float* __restrict__ W, const float* __restrict__ bias,
    float* __restrict__ out, int K, int ldw, int ldo)
{
  for (int k = threadIdx.x; k < K; k += 512){
    float b0 = bias ? bias[k] : 0.f;
    float acc[16];
    #pragma unroll
    for (int r=0;r<16;r++) acc[r] = b0;
    int i = 0;
    for (; i+4 <= 148; i += 4){
      float w0 = W[(size_t)i*ldw + k];
      float w1 = W[(size_t)(i+1)*ldw + k];
      float w2 = W[(size_t)(i+2)*ldw + k];
      float w3 = W[(size_t)(i+3)*ldw + k];
      #pragma unroll
      for (int r=0;r<16;r++){
        float4 xv = *(const float4*)&xs[r][i];
        acc[r] = fmaf(xv.x, w0, acc[r]);
        acc[r] = fmaf(xv.y, w1, acc[r]);
        acc[r] = fmaf(xv.z, w2, acc[r]);
        acc[r] = fmaf(xv.w, w3, acc[r]);
      }
    }
    {
      float w0 = W[(size_t)148*ldw + k];
      float w1 = W[(size_t)149*ldw + k];
      #pragma unroll
      for (int r=0;r<16;r++){
        acc[r] = fmaf(xs[r][148], w0, acc[r]);
        acc[r] = fmaf(xs[r][149], w1, acc[r]);
      }
    }
    for (int r=0;r<nr;r++) out[(size_t)(r0+r)*ldo + k] = acc[r];
  }
  for (int k = K + threadIdx.x; k < ldo; k += 512)
    for (int r=0;r<nr;r++) out[(size_t)(r0+r)*ldo + k] = 0.f;
}

__global__ __launch_bounds__(512) void rowproj16_3_kernel(
    const float* __restrict__ X, int rows,
    const float* __restrict__ W0, const float* __restrict__ b0, float* __restrict__ o0,
    int K0, int ldw0, int ldo0,
    const float* __restrict__ W1, const float* __restrict__ b1, float* __restrict__ o1,
    int K1, int ldw1, int ldo1,
    const float* __restrict__ W2, const float* __restrict__ b2, float* __restrict__ o2,
    int K2, int ldw2, int ldo2)
{
  __shared__ __align__(16) float xs[16][152];
  const int r0 = blockIdx.x*16;
  int nr = rows - r0; if (nr > 16) nr = 16;
  if (nr <= 0) return;
  for (int e = threadIdx.x; e < nr*150; e += 512){
    int r = e/150, i = e - r*150;
    xs[r][i] = X[(size_t)(r0+r)*150 + i];
  }
  if (threadIdx.x < 32){
    int r = threadIdx.x/2, i = 150 + (threadIdx.x&1);
    if (r < 16) xs[r][i] = 0.f;
  }
  __syncthreads();
  rowproj_one(xs, nr, r0, W0, b0, o0, K0, ldw0, ldo0);
  rowproj_one(xs, nr, r0, W1, b1, o1, K1, ldw1, ldo1);
  rowproj_one(xs, nr, r0, W2, b2, o2, K2, ldw2, ldo2);
}

// ---- register macros ------------------------------------------------------
#define R26(M) M(0) M(1) M(2) M(3) M(4) M(5) M(6) M(7) M(8) M(9) M(10) M(11) \
               M(12) M(13) M(14) M(15) M(16) M(17) M(18) M(19) M(20) M(21) \
               M(22) M(23) M(24) M(25)
#define R12(M) M(26) M(27) M(28) M(29) M(30) M(31) M(32) M(33) M(34) M(35) \
               M(36) M(37)
#define DECW(i) float4 w##i;
#define LDW(i)  w##i = wrow4[i];
#define LDW2(i) w##i = s2q4[(i-26)*s2stride + s2r];
#define FMAW(i) { float4 hq = h4[i]; \
  acc0 = fmaf(hq.x, w##i.x, acc0); acc1 = fmaf(hq.y, w##i.y, acc1); \
  acc2 = fmaf(hq.z, w##i.z, acc2); acc3 = fmaf(hq.w, w##i.w, acc3); }

// ---- merged GRU encoder scan: blocks 0..31 context (S=400), 32..63 query (S=30)
// gi loads pipelined one step ahead (load t+1 during step t) so phase E
// never waits on HBM latency.
__global__ __launch_bounds__(512, 2) void gru_scan_kernel(
    const float* __restrict__ gi0, const float* __restrict__ Wp0,
    const float* __restrict__ s2q0, const float* __restrict__ bh0,
    float* __restrict__ H0, int S0,
    const float* __restrict__ gi1, const float* __restrict__ Wp1,
    const float* __restrict__ s2q1, const float* __restrict__ bh1,
    float* __restrict__ H1, int S1)
{
  const int blk = blockIdx.x;
  const float* gi; const float* Wpad; const float* s2qG; const float* bh; float* Hs; int S;
  if (blk < 32){ gi = gi0 + (size_t)blk*S0*450;  Wpad = Wp0; s2qG = s2q0; bh = bh0;
                 Hs = H0 + (size_t)blk*S0*150;   S = S0; }
  else         { int bb = blk-32;
                 gi = gi1 + (size_t)bb*S1*450;   Wpad = Wp1; s2qG = s2q1; bh = bh1;
                 Hs = H1 + (size_t)bb*S1*150;    S = S1; }
  __shared__ __align__(16) float h[152];
  __shared__ float gh[452];
  const int tid = threadIdx.x;

  R26(DECW) R12(DECW)
  float br = 0.f;
  {
    const float4* wrow4 = (const float4*)(Wpad + (size_t)((tid<450)?tid:0)*152);
    R26(LDW)
    const float4* s2q4 = (const float4*)s2qG;
    const int s2stride = 452; const int s2r = (tid<452) ? tid : 0;
    R12(LDW2)
    if (tid<450) br = bh[tid];
  }
  if (tid < 152) h[tid] = 0.f;
  __syncthreads();
  const float4* h4 = (const float4*)h;

  float g0=0.f,g1=0.f,g2=0.f;
  if (tid < 150){
    g0 = gi[tid]; g1 = gi[150+tid]; g2 = gi[300+tid];
  }
  for (int t=0;t<S;t++){
    float n0=0.f,n1=0.f,n2=0.f;
    if (tid < 150 && t+1 < S){
      const float* gg = gi + (size_t)(t+1)*450;
      n0 = gg[tid]; n1 = gg[150+tid]; n2 = gg[300+tid];
    }
    if (tid < 450){
      float acc0=br, acc1=0.f, acc2=0.f, acc3=0.f;
      R26(FMAW) R12(FMAW)
      gh[tid] = (acc0+acc2)+(acc1+acc3);
    }
    bar_lds();
    if (tid < 150){
      float r = sigm(g0 + gh[tid]);
      float z = sigm(g1 + gh[150+tid]);
      float n = tanh_f(g2 + r*gh[300+tid]);
      float hn = (1.f-z)*n + z*h[tid];
      h[tid] = hn;
      Hs[(size_t)t*150 + tid] = hn;
    }
    bar_lds();
    g0 = n0; g1 = n1; g2 = n2;
  }
}

// ---- match scan: one block per (batch, dir); 512 threads; 3 LDS-only
// barriers/step. 38 weight quads in registers (R14 parked set); extW,
// whq, wl in LDS; in-thread softmax; PsT b128 gate dots; wave_sum64.
// Prologue also zeroes Hr[b][0][dir half] (zero_hr0 kernel folded in).
__global__ __launch_bounds__(512, 2) void match_scan_kernel(
    const float* __restrict__ pWp,   // [B,T,152]
    const float* __restrict__ whq,   // [B,J,152]
    const float* __restrict__ giXf,  // [B,T,452]
    const float* __restrict__ giXr,
    const float* __restrict__ Pf,    // [B,J,452]
    const float* __restrict__ Pr,
    const float* __restrict__ WcatF, const float* __restrict__ WcatR, // [600][152]
    const float* __restrict__ s2qF,  const float* __restrict__ s2qR,  // [12][512] f4
    const float* __restrict__ extF,  const float* __restrict__ extR,  // [38][88] f4
    const float* __restrict__ m_bhh, const float* __restrict__ mr_bhh,
    const float* __restrict__ wvec,  // [150]
    float* __restrict__ Hr)          // [B,401,300]
{
  const int b   = blockIdx.x;
  const int dir = blockIdx.y;
  const float* giX  = dir ? giXr : giXf;
  const float* P    = dir ? Pr   : Pf;
  const float* Wcat = dir ? WcatR : WcatF;
  const float* s2qG = dir ? s2qR  : s2qF;
  const float* extG = dir ? extR  : extF;
  const float* bhh  = dir ? mr_bhh : m_bhh;

  __shared__ float4 extW[3344];                // 53,504
  __shared__ __align__(16) float PsT[15000];   // 60,000  [150][100]: k*100+g*32+j
  __shared__ __align__(16) float whqS[JQ*152]; // 18,240
  __shared__ __align__(16) float wrP[760];     //  3,040  [5][152], k-indexed
  __shared__ __align__(16) float h[152];       //    608
  __shared__ float ghsRaw[512];                //  2,048
  __shared__ __align__(16) float pwS[152];     //    608
  __shared__ __align__(16) float wlS[152];     //    608
  __shared__ __align__(16) float sc[32];       //    128  [30..31] = -1e30
                                               // -> 138,784 B
  const int tid  = threadIdx.x;
  const int lane = tid & 63;
  const int wv   = tid >> 6;
  const int er   = (tid < 440) ? (tid % 88) : 0;   // ext row index (k=62+er)
  const int kg   = (tid < 440) ? (tid / 88) : 0;   // ext K-group / wrP segment

  R26(DECW) R12(DECW)
  float br;
  {
    const float4* wrow4 = (const float4*)(Wcat + (size_t)tid*152);
    R26(LDW)
    const float4* s2q4 = (const float4*)s2qG;
    const int s2stride = 512; const int s2r = tid;
    R12(LDW2)
    br = (tid < 450) ? bhh[tid] : 0.f;
  }
  for (int e=tid; e<3344; e+=512) extW[e] = ((const float4*)extG)[e];
  {
    const float4* wq4 = (const float4*)(whq + (size_t)b*JQ*152);
    for (int e=tid; e<JQ*38; e+=512) ((float4*)whqS)[e] = wq4[e];
  }
  for (int e=tid; e<15000; e+=512) PsT[e] = 0.f;
  for (int e=tid; e<760;   e+=512) wrP[e] = 0.f;
  if (tid < 152){
    h[tid] = 0.f;
    wlS[tid] = (tid<150) ? wvec[tid] : 0.f;
  }
  if (tid >= 30 && tid < 32) sc[tid] = -1e30f;
  if (tid < 150) Hr[(size_t)b*T1*300 + dir*150 + tid] = 0.f;  // t=0 row zero
  __syncthreads();
  {
    const float* Pb = P + (size_t)b*JQ*452;
    for (int e=tid; e<JQ*452; e+=512){
      int j = e/452, kk = e - j*452;
      if (kk < 450){
        int g = kk/150, k = kk - g*150;
        PsT[k*100 + g*32 + j] = Pb[e];
      }
    }
  }
  __syncthreads();
  const float4* h4 = (const float4*)h;
  const float4* wrP4 = (const float4*)wrP;

  for (int t=0;t<TLEN;t++){
    const int tt = dir ? (TLEN-1-t) : t;

    // ---- prefetch (issued before phase A; vmcnt waits at use sites) ----
    float gv0=0.f, gv1=0.f, gv2=0.f;
    if (tid < 150){
      const float* g = giX + ((size_t)b*TLEN + tt)*452;
      gv0 = g[tid]; gv1 = g[150+tid]; gv2 = g[300+tid];
    }
    float4 pwv;
    if (tid >= 440 && tid < 478)
      pwv = ((const float4*)(pWp + ((size_t)b*TLEN + tt)*152))[tid-440];

    // A: row dots for rows 0..511 (38 register quads; only h from LDS)
    {
      float acc0=br, acc1=0.f, acc2=0.f, acc3=0.f;
      R26(FMAW) R12(FMAW)
      float v = (acc0+acc2)+(acc1+acc3);
      ghsRaw[tid] = v;
      if (tid >= 450) wrP[tid-450] = v;        // seg0, k=0..61
    }
    // A-ext: Wcat rows 512..599 (Wr outputs k=62..149), 5 K-groups x 88 rows
    if (tid < 440){
      float e0=0.f, e1=0.f;
      #pragma unroll
      for (int j=0;j<8;j++){
        int q = kg*8+j;
        if (q < 38){
          float4 wq = extW[q*88+er]; float4 hq = h4[q];
          e0 = fmaf(hq.x,wq.x,e0); e1 = fmaf(hq.y,wq.y,e1);
          e0 = fmaf(hq.z,wq.z,e0); e1 = fmaf(hq.w,wq.w,e1);
        }
      }
      wrP[kg*152 + 62 + er] = e0+e1;
    }
    if (tid >= 440 && tid < 478) ((float4*)pwS)[tid-440] = pwv;
    bar_lds();                             // b1 (LDS-only)

    // B: scores; base from pwS+wrP, whq/w from LDS; VALU-dominant reduce
    {
      float4 b4 = make_float4(0.f,0.f,0.f,0.f);
      const bool bl = (lane < 38);
      if (bl){
        float4 pw4 = ((const float4*)pwS)[lane];
        float4 s0 = wrP4[lane],        s1 = wrP4[38+lane];
        float4 s2 = wrP4[76+lane],     s3 = wrP4[114+lane];
        float4 s4 = wrP4[152+lane];
        b4.x = pw4.x + s0.x+s1.x+s2.x+s3.x+s4.x;
        b4.y = pw4.y + s0.y+s1.y+s2.y+s3.y+s4.y;
        b4.z = pw4.z + s0.z+s1.z+s2.z+s3.z+s4.z;
        b4.w = pw4.w + s0.w+s1.w+s2.w+s3.w+s4.w;
      }
      #pragma unroll
      for (int jj=0;jj<4;jj++){
        int j = wv + 8*jj;
        float a = 0.f;
        if (j < JQ && bl){
          float4 q4 = ((const float4*)whqS)[j*38 + lane];
          float4 w4 = ((const float4*)wlS)[lane];
          a = w4.x*tanh_f(q4.x+b4.x);
          a = fmaf(w4.y, tanh_f(q4.y+b4.y), a);
          a = fmaf(w4.z, tanh_f(q4.z+b4.z), a);
          a = fmaf(w4.w, tanh_f(q4.w+b4.w), a);
        }
        a = wave_sum64(a);
        if (j < JQ && lane==0) sc[j] = a;
      }
    }
    bar_lds();                             // b2 (LDS-only)

    // C+D+E: in-thread softmax (8 broadcast b128, zero shuffles), then
    // 24 b128 PsT reads for the three gate dots, then GRU combine.
    if (tid < 192){
      const float4* sc4 = (const float4*)sc;
      float4 s0=sc4[0], s1=sc4[1], s2=sc4[2], s3=sc4[3];
      float4 s4=sc4[4], s5=sc4[5], s6=sc4[6], s7=sc4[7];
      float m = fmaxf(fmaxf(fmaxf(q4max(s0),q4max(s1)),fmaxf(q4max(s2),q4max(s3))),
                      fmaxf(fmaxf(q4max(s4),q4max(s5)),fmaxf(q4max(s6),q4max(s7))));
      float4 a0=exp4(s0,m), a1=exp4(s1,m), a2=exp4(s2,m), a3=exp4(s3,m);
      float4 a4=exp4(s4,m), a5=exp4(s5,m), a6=exp4(s6,m), a7=exp4(s7,m);
      float su = ((sum4(a0)+sum4(a1))+(sum4(a2)+sum4(a3)))
               + ((sum4(a4)+sum4(a5))+(sum4(a6)+sum4(a7)));
      float inv = 1.f/su;
      a0=scl4(a0,inv); a1=scl4(a1,inv); a2=scl4(a2,inv); a3=scl4(a3,inv);
      a4=scl4(a4,inv); a5=scl4(a5,inv); a6=scl4(a6,inv); a7=scl4(a7,inv);
      const int k = (tid < 150) ? tid : 0;
      const float4* Pk = (const float4*)(PsT + k*100);
      float accr = gv0, accz = gv1, accn = gv2;
      #define ACC1(acc,P4,A4){ float4 p=P4; \
        acc=fmaf(A4.x,p.x,acc); acc=fmaf(A4.y,p.y,acc); \
        acc=fmaf(A4.z,p.z,acc); acc=fmaf(A4.w,p.w,acc); }
      #define ACCG(acc,g){ ACC1(acc,Pk[g*8+0],a0) ACC1(acc,Pk[g*8+1],a1) \
        ACC1(acc,Pk[g*8+2],a2) ACC1(acc,Pk[g*8+3],a3) ACC1(acc,Pk[g*8+4],a4) \
        ACC1(acc,Pk[g*8+5],a5) ACC1(acc,Pk[g*8+6],a6) ACC1(acc,Pk[g*8+7],a7) }
      ACCG(accr,0) ACCG(accz,1) ACCG(accn,2)
      #undef ACC1
      #undef ACCG
      if (tid < 150){
        float r = sigm(accr + ghsRaw[tid]);
        float z = sigm(accz + ghsRaw[150+tid]);
        float n = tanh_f(accn + r*ghsRaw[300+tid]);
        float hn = (1.f-z)*n + z*h[tid];
        h[tid] = hn;
        Hr[((size_t)b*T1 + (t+1))*300 + dir*150 + tid] = hn;
      }
    }
    bar_lds();                             // b3 (LDS-only; Hr store in flight)
  }
}

// ---- pointer decoder
__global__ __launch_bounds__(512,2) void ptr_scan_kernel(
    const float* __restrict__ enc, const float* __restrict__ Hr,
    const float* __restrict__ W2, const float* __restrict__ pv,
    const float* __restrict__ dWih, const float* __restrict__ dWhh,
    const float* __restrict__ dbih, const float* __restrict__ dbhh,
    void* __restrict__ outv, const int* __restrict__ flag)
{
  const int b = blockIdx.x;
  const int tid = threadIdx.x;
  const int isbf = *flag;
  __shared__ float h[300], hW2[300], sl[T1], al[T1], c[300];
  __shared__ float gis[900], ghs[900];
  __shared__ float vl[300];
  __shared__ float red[8];
  if (tid < 300){ h[tid] = 0.f; vl[tid] = pv[tid]; }
  __syncthreads();
  for (int l=0;l<2;l++){
    if (tid < 300){
      float a0=0.f,a1=0.f;
      for (int i=0;i<300;i+=2){
        a0 += h[i]  *W2[(size_t)i*300+tid];
        a1 += h[i+1]*W2[(size_t)(i+1)*300+tid];
      }
      hW2[tid] = a0+a1;
    }
    __syncthreads();
    {
      const int wv = tid>>6, lane = tid&63;
      for (int t=wv; t<T1; t+=8){
        const float* er = enc + ((size_t)b*T1 + t)*300;
        float acc = 0.f;
        for (int k=lane; k<300; k+=64) acc += vl[k]*tanh_f(er[k] + hW2[k]);
        #pragma unroll
        for (int off=32; off; off>>=1) acc += __shfl_down(acc, off);
        if (lane==0) sl[t] = acc;
      }
    }
    __syncthreads();
    {
      float v = (tid < T1) ? sl[tid] : -1e30f;
      float m = v;
      #pragma unroll
      for (int off=32; off; off>>=1) m = fmaxf(m, __shfl_down(m, off));
      if ((tid&63)==0) red[tid>>6] = m;
      __syncthreads();
      float bm = fmaxf(fmaxf(fmaxf(red[0],red[1]),fmaxf(red[2],red[3])),
                       fmaxf(fmaxf(red[4],red[5]),fmaxf(red[6],red[7])));
      float e = (tid < T1) ? __expf(v-bm) : 0.f;
      float su = e;
      #pragma unroll
      for (int off=32; off; off>>=1) su += __shfl_down(su, off);
      __syncthreads();
      if ((tid&63)==0) red[tid>>6] = su;
      __syncthreads();
      float bs = red[0]+red[1]+red[2]+red[3]+red[4]+red[5]+red[6]+red[7];
      if (tid < T1){
        float a = e/bs;
        al[tid] = a;
        size_t oi = ((size_t)b*2 + l)*T1 + tid;
        if (isbf) ((__hip_bfloat16*)outv)[oi] = __float2bfloat16(a);
        else      ((float*)outv)[oi] = a;
      }
    }
    __syncthreads();
    if (tid < 300){
      float acc = 0.f;
      for (int t=0;t<T1;t++) acc += al[t]*Hr[((size_t)b*T1 + t)*300 + tid];
      c[tid] = acc;
    }
    __syncthreads();
    for (int k=tid; k<900; k+=blockDim.x){
      const float* wi = dWih + (size_t)k*300;
      const float* wh = dWhh + (size_t)k*300;
      float a0 = dbih[k], a1 = dbhh[k];
      for (int i=0;i<300;i++){ a0 += c[i]*wi[i]; a1 += h[i]*wh[i]; }
      gis[k] = a0; ghs[k] = a1;
    }
    __syncthreads();
    if (tid < 300){
      float r = sigm(gis[tid] + ghs[tid]);
      float z = sigm(gis[300+tid] + ghs[300+tid]);
      float n = tanh_f(gis[600+tid] + r*ghs[600+tid]);
      h[tid] = (1.f-z)*n + z*h[tid];
    }
    __syncthreads();
  }
}

} // namespace

extern "C" void kernel_launch(void* const* d_in, const int* in_sizes, int n_in,
                              void* d_out, int out_size, void* d_ws, size_t ws_size,
                              hipStream_t stream)
{
  (void)in_sizes; (void)n_in; (void)out_size; (void)ws_size;
  float* ws = (float*)d_ws;
  int* flag = (int*)d_ws;

  static const int wsz[NW] = {
    67500,67500,450,450,
    67500,67500,450,450,
    22500,22500,22500,150,150,1,
    135000,67500,450,450,
    135000,67500,450,450,
    90000,90000,300,
    270000,270000,900,900
  };
  WDesc desc;
  int cum = 0;
  for (int j=0;j<NW;j++){ desc.src[j] = d_in[3+j]; desc.off[j] = cum; cum += wsz[j]; }
  desc.off[NW] = cum;

  float* WB = ws + 16;
  const float* P_ctx_Wih = WB + desc.off[0];
  const float* P_ctx_Whh = WB + desc.off[1];
  const float* P_ctx_bih = WB + desc.off[2];
  const float* P_ctx_bhh = WB + desc.off[3];
  const float* P_q_Wih   = WB + desc.off[4];
  const float* P_q_Whh   = WB + desc.off[5];
  const float* P_q_bih   = WB + desc.off[6];
  const float* P_q_bhh   = WB + desc.off[7];
  const float* P_Wq      = WB + desc.off[8];
  const float* P_Wp      = WB + desc.off[9];
  const float* P_Wr      = WB + desc.off[10];
  const float* P_w       = WB + desc.off[11];
  const float* P_gb      = WB + desc.off[12];
  const float* P_m_Wih   = WB + desc.off[14];
  const float* P_m_Whh   = WB + desc.off[15];
  const float* P_m_bih   = WB + desc.off[16];
  const float* P_m_bhh   = WB + desc.off[17];
  const float* P_mr_Wih  = WB + desc.off[18];
  const float* P_mr_Whh  = WB + desc.off[19];
  const float* P_mr_bih  = WB + desc.off[20];
  const float* P_mr_bhh  = WB + desc.off[21];
  const float* P_W1      = WB + desc.off[22];
  const float* P_W2      = WB + desc.off[23];
  const float* P_pv      = WB + desc.off[24];
  const float* P_dWih    = WB + desc.off[25];
  const float* P_dWhh    = WB + desc.off[26];
  const float* P_dbih    = WB + desc.off[27];
  const float* P_dbhh    = WB + desc.off[28];

  size_t p = 16 + 1468512;
  float* ctxWhhP = ws + p; p += 68400;    // [450][152]
  float* qWhhP   = ws + p; p += 68400;
  float* s2qCtx  = ws + p; p += 21696;    // [12][452] f4
  float* s2qQ    = ws + p; p += 21696;
  float* WcatF   = ws + p; p += 91200;    // [600][152]
  float* WcatR   = ws + p; p += 91200;
  float* s2qF    = ws + p; p += 24576;    // [12][512] f4
  float* s2qR    = ws + p; p += 24576;
  float* extFg   = ws + p; p += 13376;    // [38][88] f4
  float* extRg   = ws + p; p += 13376;
  // transposed input-projection weights (mode-0 layouts)
  float* ctxWihT = ws + p; p += 67500;    // [150][450]
  float* qWihT   = ws + p; p += 67500;
  float* mXfT    = ws + p; p += 67500;    // m_Wih cols 0..149   -> [150][450]
  float* mXrT    = ws + p; p += 67500;
  float* mQfT    = ws + p; p += 67500;    // m_Wih cols 150..299 -> [150][450]
  float* mQrT    = ws + p; p += 67500;

  float* ctx_gi = ws + p; p += 5760000;   // [B,T,450]; reused as enc later
  float* q_gi   = ws + p; p += 432000;    // [B,J,450]
  float* HpB    = ws + p; p += 1920000;   // [B,T,150]
  float* HqB    = ws + p; p += 144000;    // [B,J,150]
  float* whqB   = ws + p; p += 145920;    // [B,J,152]
  float* PfB    = ws + p; p += 433920;    // [B,J,452]
  float* PrB    = ws + p; p += 433920;
  float* pWpB   = ws + p; p += 1945600;   // [B,T,152]
  float* giXfB  = ws + p; p += 5785600;   // [B,T,452]
  float* giXrB  = ws + p; p += 5785600;
  float* HrB    = ws + p; p += 3849600;   // [B,401,300]
  float* encB   = ctx_gi;                 // [B,401,300]

  // 1) dtype sniff + weight conversion + fused restructure
  sniff_kernel<<<1,256,0,stream>>>((const unsigned int*)d_in[2], flag);
  convert_weights_kernel<<<512,256,0,stream>>>(desc, WB, flag);
  {
    PrepArgs a;
    a.ctxWhh = P_ctx_Whh; a.qWhh = P_q_Whh; a.mWhh = P_m_Whh; a.mrWhh = P_mr_Whh;
    a.Wr = P_Wr; a.ctxWih = P_ctx_Wih; a.qWih = P_q_Wih; a.mWih = P_m_Wih; a.mrWih = P_mr_Wih;
    a.ctxWhhP = ctxWhhP; a.qWhhP = qWhhP; a.s2qCtx = s2qCtx; a.s2qQ = s2qQ;
    a.WcatF = WcatF; a.WcatR = WcatR; a.s2qF = s2qF; a.s2qR = s2qR;
    a.extF = extFg; a.extR = extRg; a.ctxWihT = ctxWihT; a.qWihT = qWihT;
    a.mXfT = mXfT; a.mXrT = mXrT; a.mQfT = mQfT; a.mQrT = mQrT;
    prep_all_kernel<<<2048,256,0,stream>>>(a);
  }

  // 2) embedding + input projections for both encoders (mode-0, 16-row tiles)
  rowproj16_kernel<<<800,512,0,stream>>>(nullptr,(const int*)d_in[0], d_in[2], flag,
                                         ctxWihT, P_ctx_bih, ctx_gi, 12800,450,150,450,450);
  rowproj16_kernel<<<60,512,0,stream>>>(nullptr,(const int*)d_in[1], d_in[2], flag,
                                        qWihT, P_q_bih, q_gi, 960,450,150,450,450);

  // 3) encoder scans
  gru_scan_kernel<<<64,512,0,stream>>>(ctx_gi, ctxWhhP, s2qCtx, P_ctx_bhh, HpB, 400,
                                       q_gi,   qWhhP,   s2qQ,   P_q_bhh,   HqB, 30);

  // 4) Hq/Hp-dependent precomputations (fused triples)
  rowproj16_3_kernel<<<60,512,0,stream>>>(HqB, 960,
      P_Wq, nullptr, whqB, 150, 150, 152,
      mQfT, nullptr, PfB, 450, 450, 452,
      mQrT, nullptr, PrB, 450, 450, 452);
  rowproj16_3_kernel<<<800,512,0,stream>>>(HpB, 12800,
      P_Wp, P_gb, pWpB, 150, 150, 152,
      mXfT, P_m_bih, giXfB, 450, 450, 452,
      mXrT, P_mr_bih, giXrB, 450, 450, 452);

  // 5) match scans (fwd+bwd concurrent; t=0 Hr row zeroed in prologue)
  match_scan_kernel<<<dim3(NBATCH,2),512,0,stream>>>(pWpB, whqB, giXfB, giXrB,
                                                     PfB, PrB, WcatF, WcatR,
                                                     s2qF, s2qR, extFg, extRg,
                                                     P_m_bhh, P_mr_bhh, P_w, HrB);

  // 6) pointer decoder
  rowproj16_kernel<<<802,512,0,stream>>>(HrB,nullptr,nullptr,nullptr, P_W1, nullptr,
                                         encB, 12832,300,300,300,300);
  ptr_scan_kernel<<<32,512,0,stream>>>(encB, HrB, P_W2, P_pv,
                                       P_dWih, P_dWhh, P_dbih, P_dbhh, d_out, flag);
}

// Round 9
// 3090.183 us; speedup vs baseline: 1.0078x; 1.0078x over previous
//
#include <hip/hip_runtime.h>
#include <hip/hip_bf16.h>

// MatchLSTM boundary-pointer model on MI355X (gfx950).
// B=32 T=400 J=30 V=50000 D=150 H=150 L=2. Output [B,2,401].
//
// Round 18 = round 17 (3114us ~= R16 3090us noise; match_scan 1657-1668)
// + lane-utilization fixes OUTSIDE match_scan:
//  1) rowproj16_3: three sequential k-passes (K=150/450/450 vs 512-thread
//     stride = 68% util; K=150 pass idles 71% of lanes) fused into ONE
//     k-loop over 1050 virtual columns with per-thread segment select.
//     ~2.05 full-width iterations instead of 3.
//  2) rowproj16: strides parameterized by blockDim.x; enc launch (K=300)
//     moved 512->320 threads (59% -> 94% k-loop utilization).
//  match_scan and gru_scan unchanged from R17.

namespace {

constexpr int NBATCH = 32;
constexpr int TLEN   = 400;
constexpr int JQ     = 30;
constexpr int T1     = 401;

__device__ __forceinline__ float sigm(float x){ return 1.f/(1.f+__expf(-x)); }
__device__ __forceinline__ float tanh_f(float x){
  float e = __expf(-2.f*fabsf(x));
  float t = (1.f-e)/(1.f+e);
  return x < 0.f ? -t : t;
}
__device__ __forceinline__ float bf2f(unsigned short u){
  union { unsigned int i; float f; } c; c.i = ((unsigned int)u)<<16; return c.f;
}
__device__ __forceinline__ float q4max(float4 v){ return fmaxf(fmaxf(v.x,v.y),fmaxf(v.z,v.w)); }
__device__ __forceinline__ float sum4(float4 v){ return (v.x+v.y)+(v.z+v.w); }
__device__ __forceinline__ float4 exp4(float4 v, float m){
  return make_float4(__expf(v.x-m),__expf(v.y-m),__expf(v.z-m),__expf(v.w-m));
}
__device__ __forceinline__ float4 scl4(float4 v, float s){
  return make_float4(v.x*s,v.y*s,v.z*s,v.w*s);
}

// Wave-64 sum with 1 DS op (vs 6 bpermutes): permlane32_swap (VALU) +
// ds_swizzle xor16 (DS) + DPP row_shr 8/4/2/1 adds (VALU). Total lands
// in lane 0 (also lanes 16/32/48).
__device__ __forceinline__ float wave_sum64(float a){
  float x = a, y = a;
  asm volatile("v_permlane32_swap_b32 %0, %1" : "+v"(x), "+v"(y));
  a = x + y;                                   // all lanes: lo+hi pair sum
  a += __int_as_float(__builtin_amdgcn_ds_swizzle(__float_as_int(a), 0x401F)); // ^16
  a += __int_as_float(__builtin_amdgcn_update_dpp(0, __float_as_int(a), 0x118, 0xF, 0xF, true));
  a += __int_as_float(__builtin_amdgcn_update_dpp(0, __float_as_int(a), 0x114, 0xF, 0xF, true));
  a += __int_as_float(__builtin_amdgcn_update_dpp(0, __float_as_int(a), 0x112, 0xF, 0xF, true));
  a += __int_as_float(__builtin_amdgcn_update_dpp(0, __float_as_int(a), 0x111, 0xF, 0xF, true));
  return a;
}

// LDS-only barrier: orders LDS producer->consumer across waves without
// draining vmcnt (global prefetch loads / stores stay in flight).
__device__ __forceinline__ void bar_lds(){
  asm volatile("s_waitcnt lgkmcnt(0)" ::: "memory");
  __builtin_amdgcn_s_barrier();
}

#define NW 29
struct WDesc { const void* src[NW]; int off[NW+1]; };

__global__ void sniff_kernel(const unsigned int* __restrict__ bits, int* __restrict__ flag){
  __shared__ int cnt;
  if (threadIdx.x==0) cnt = 0;
  __syncthreads();
  int hit = 0;
  #pragma unroll
  for (int i=0;i<4;i++){
    unsigned int w = bits[threadIdx.x*4+i];
    unsigned int b = (w>>8)&0x7Fu;
    if (b==0u || (b>=0x38u && b<=0x3Fu)) hit++;
  }
  atomicAdd(&cnt, hit);
  __syncthreads();
  if (threadIdx.x==0) *flag = (cnt > 768) ? 1 : 0;
}

__global__ void convert_weights_kernel(WDesc d, float* __restrict__ out, const int* __restrict__ flag){
  const int isbf = *flag;
  const int total = d.off[NW];
  for (int e = blockIdx.x*blockDim.x+threadIdx.x; e < total; e += gridDim.x*blockDim.x){
    int j = 0;
    while (e >= d.off[j+1]) j++;
    int i = e - d.off[j];
    out[e] = isbf ? bf2f(((const unsigned short*)d.src[j])[i])
                  : ((const float*)d.src[j])[i];
  }
}

// ---- fused weight-restructure kernel ----------
struct PrepArgs {
  const float *ctxWhh, *qWhh, *mWhh, *mrWhh, *Wr;
  const float *ctxWih, *qWih, *mWih, *mrWih;
  float *ctxWhhP, *qWhhP, *s2qCtx, *s2qQ, *WcatF, *WcatR, *s2qF, *s2qR;
  float *extF, *extR, *ctxWihT, *qWihT, *mXfT, *mXrT, *mQfT, *mQrT;
};

__global__ void prep_all_kernel(PrepArgs a){
  const int PN[16] = {68400,68400,21696,21696,91200,91200,24576,24576,
                      13376,13376,67500,67500,67500,67500,67500,67500};
  const int TOT = 843496;
  for (int gid = blockIdx.x*blockDim.x+threadIdx.x; gid < TOT; gid += gridDim.x*blockDim.x){
    int e = gid, t = 0;
    while (e >= PN[t]){ e -= PN[t]; t++; }
    switch (t){
      case 0: case 1: {                       // padrows Whh -> [450][152]
        const float* s = (t==0)? a.ctxWhh : a.qWhh;
        float* d = (t==0)? a.ctxWhhP : a.qWhhP;
        int r = e/152, c = e-r*152;
        d[e] = (c<150) ? s[r*150+c] : 0.f;
      } break;
      case 2: case 3: {                       // gsplit: [12][452] f4
        const float* s = (t==2)? a.ctxWhh : a.qWhh;
        float* d = (t==2)? a.s2qCtx : a.s2qQ;
        int q = e/1808, rem = e-q*1808, r = rem/4, p = rem-r*4;
        int c = 104 + 4*q + p;
        d[e] = (r<450 && c<150) ? s[(size_t)r*150+c] : 0.f;
      } break;
      case 4: case 5: {                       // Wcat [600][152]
        const float* s = (t==4)? a.mWhh : a.mrWhh;
        float* d = (t==4)? a.WcatF : a.WcatR;
        int r = e/152, c = e-r*152;
        float v = 0.f;
        if (c < 150) v = (r<450) ? s[(size_t)r*150+c] : a.Wr[(size_t)c*150 + (r-450)];
        d[e] = v;
      } break;
      case 6: case 7: {                       // msplit s2q [12][512] f4
        const float* s = (t==6)? a.mWhh : a.mrWhh;
        float* d = (t==6)? a.s2qF : a.s2qR;
        int q = e/2048, rem = e-q*2048, r = rem/4, p = rem-r*4;
        int c = 104 + 4*q + p;
        float v = 0.f;
        if (c < 150) v = (r<450) ? s[(size_t)r*150+c] : a.Wr[(size_t)c*150 + (r-450)];
        d[e] = v;
      } break;
      case 8: case 9: {                       // ext [38][88] f4 (Wr rows 512..599)
        float* d = (t==8)? a.extF : a.extR;
        int q = e/352, rem = e-q*352, ii = rem/4, p = rem-ii*4;
        int c = 4*q + p;
        d[e] = (c<150) ? a.Wr[(size_t)c*150 + 62 + ii] : 0.f;
      } break;
      default: {                              // transposes [150][450]
        int i2 = e/450, k = e-i2*450;
        const float* s; float* d; int lds_, offs;
        switch (t){
          case 10: s=a.ctxWih; d=a.ctxWihT; lds_=150; offs=0;   break;
          case 11: s=a.qWih;   d=a.qWihT;   lds_=150; offs=0;   break;
          case 12: s=a.mWih;   d=a.mXfT;    lds_=300; offs=0;   break;
          case 13: s=a.mrWih;  d=a.mXrT;    lds_=300; offs=0;   break;
          case 14: s=a.mWih;   d=a.mQfT;    lds_=300; offs=150; break;
          default: s=a.mrWih;  d=a.mQrT;    lds_=300; offs=150; break;
        }
        d[(size_t)i2*450 + k] = s[(size_t)k*lds_ + offs + i2];
      } break;
    }
  }
}

// ---- 16-row mode-0 projection: out[r,k] = bias[k] + sum_i x[r,i]*W[i*ldw+k]
// Strides parameterized by blockDim.x so low-K launches can use fewer threads.
__global__ __launch_bounds__(512) void rowproj16_kernel(
    const float* __restrict__ Xrows,
    const int* __restrict__ gather, const void* __restrict__ Etab, const int* __restrict__ bfflag,
    const float* __restrict__ W, const float* __restrict__ bias,
    float* __restrict__ out, int rows, int K, int inner, int ldw, int ldo)
{
  __shared__ __align__(16) float xs[16][304];
  const int r0 = blockIdx.x*16;
  const int bd = blockDim.x;
  int nr = rows - r0; if (nr > 16) nr = 16;
  if (nr <= 0) return;
  const int isbf = gather ? *bfflag : 0;
  for (int e = threadIdx.x; e < nr*inner; e += bd){
    int r = e/inner, i = e - r*inner;
    float v;
    if (gather){
      size_t base = (size_t)gather[r0+r]*inner + i;
      v = isbf ? bf2f(((const unsigned short*)Etab)[base]) : ((const float*)Etab)[base];
    } else {
      v = Xrows[(size_t)(r0+r)*inner + i];
    }
    xs[r][i] = v;
  }
  __syncthreads();
  for (int k = threadIdx.x; k < K; k += bd){
    float b0 = bias ? bias[k] : 0.f;
    float acc[16];
    #pragma unroll
    for (int r=0;r<16;r++) acc[r] = b0;
    int i = 0;
    for (; i+4 <= inner; i += 4){
      float w0 = W[(size_t)i*ldw + k];
      float w1 = W[(size_t)(i+1)*ldw + k];
      float w2 = W[(size_t)(i+2)*ldw + k];
      float w3 = W[(size_t)(i+3)*ldw + k];
      #pragma unroll
      for (int r=0;r<16;r++){
        float4 xv = *(const float4*)&xs[r][i];
        acc[r] = fmaf(xv.x, w0, acc[r]);
        acc[r] = fmaf(xv.y, w1, acc[r]);
        acc[r] = fmaf(xv.z, w2, acc[r]);
        acc[r] = fmaf(xv.w, w3, acc[r]);
      }
    }
    for (; i < inner; i++){
      float wv = W[(size_t)i*ldw + k];
      #pragma unroll
      for (int r=0;r<16;r++) acc[r] = fmaf(xs[r][i], wv, acc[r]);
    }
    for (int r=0;r<nr;r++) out[(size_t)(r0+r)*ldo + k] = acc[r];
  }
  for (int k = K + threadIdx.x; k < ldo; k += bd)
    for (int r=0;r<nr;r++) out[(size_t)(r0+r)*ldo + k] = 0.f;
}

// ---- triple rowproj, FUSED single k-loop over K0+K1+K2 virtual columns.
// inner=150 fixed; xs[.][150..151]=0 padding.
__global__ __launch_bounds__(512) void rowproj16_3_kernel(
    const float* __restrict__ X, int rows,
    const float* __restrict__ W0, const float* __restrict__ b0, float* __restrict__ o0,
    int K0, int ldw0, int ldo0,
    const float* __restrict__ W1, const float* __restrict__ b1, float* __restrict__ o1,
    int K1, int ldw1, int ldo1,
    const float* __restrict__ W2, const float* __restrict__ b2, float* __restrict__ o2,
    int K2, int ldw2, int ldo2)
{
  __shared__ __align__(16) float xs[16][152];
  const int r0 = blockIdx.x*16;
  int nr = rows - r0; if (nr > 16) nr = 16;
  if (nr <= 0) return;
  for (int e = threadIdx.x; e < nr*150; e += 512){
    int r = e/150, i = e - r*150;
    xs[r][i] = X[(size_t)(r0+r)*150 + i];
  }
  if (threadIdx.x < 32){
    int r = threadIdx.x/2, i = 150 + (threadIdx.x&1);
    if (r < 16) xs[r][i] = 0.f;
  }
  __syncthreads();

  const int K01 = K0 + K1;
  const int KT  = K01 + K2;
  for (int kk = threadIdx.x; kk < KT; kk += 512){
    const float* W; const float* bias; float* out; int ldw, ldo, k;
    if (kk < K0)      { W=W0; bias=b0; out=o0; ldw=ldw0; ldo=ldo0; k=kk; }
    else if (kk < K01){ W=W1; bias=b1; out=o1; ldw=ldw1; ldo=ldo1; k=kk-K0; }
    else              { W=W2; bias=b2; out=o2; ldw=ldw2; ldo=ldo2; k=kk-K01; }
    float bv = bias ? bias[k] : 0.f;
    float acc[16];
    #pragma unroll
    for (int r=0;r<16;r++) acc[r] = bv;
    int i = 0;
    for (; i+4 <= 148; i += 4){
      float w0 = W[(size_t)i*ldw + k];
      float w1 = W[(size_t)(i+1)*ldw + k];
      float w2 = W[(size_t)(i+2)*ldw + k];
      float w3 = W[(size_t)(i+3)*ldw + k];
      #pragma unroll
      for (int r=0;r<16;r++){
        float4 xv = *(const float4*)&xs[r][i];
        acc[r] = fmaf(xv.x, w0, acc[r]);
        acc[r] = fmaf(xv.y, w1, acc[r]);
        acc[r] = fmaf(xv.z, w2, acc[r]);
        acc[r] = fmaf(xv.w, w3, acc[r]);
      }
    }
    {
      float w0 = W[(size_t)148*ldw + k];
      float w1 = W[(size_t)149*ldw + k];
      #pragma unroll
      for (int r=0;r<16;r++){
        acc[r] = fmaf(xs[r][148], w0, acc[r]);
        acc[r] = fmaf(xs[r][149], w1, acc[r]);
      }
    }
    for (int r=0;r<nr;r++) out[(size_t)(r0+r)*ldo + k] = acc[r];
  }
  // zero pad columns (each output has ldo-K == 2)
  for (int e = threadIdx.x; e < 6; e += 512){
    int seg = e>>1, c = e&1;
    float* out; int K, ldo;
    if (seg==0){ out=o0; K=K0; ldo=ldo0; }
    else if (seg==1){ out=o1; K=K1; ldo=ldo1; }
    else { out=o2; K=K2; ldo=ldo2; }
    int col = K + c;
    if (col < ldo)
      for (int r=0;r<nr;r++) out[(size_t)(r0+r)*ldo + col] = 0.f;
  }
}

// ---- register macros ------------------------------------------------------
#define R26(M) M(0) M(1) M(2) M(3) M(4) M(5) M(6) M(7) M(8) M(9) M(10) M(11) \
               M(12) M(13) M(14) M(15) M(16) M(17) M(18) M(19) M(20) M(21) \
               M(22) M(23) M(24) M(25)
#define R12(M) M(26) M(27) M(28) M(29) M(30) M(31) M(32) M(33) M(34) M(35) \
               M(36) M(37)
#define DECW(i) float4 w##i;
#define LDW(i)  w##i = wrow4[i];
#define LDW2(i) w##i = s2q4[(i-26)*s2stride + s2r];
#define FMAW(i) { float4 hq = h4[i]; \
  acc0 = fmaf(hq.x, w##i.x, acc0); acc1 = fmaf(hq.y, w##i.y, acc1); \
  acc2 = fmaf(hq.z, w##i.z, acc2); acc3 = fmaf(hq.w, w##i.w, acc3); }

// ---- merged GRU encoder scan: blocks 0..31 context (S=400), 32..63 query (S=30)
// gi loads pipelined one step ahead (load t+1 during step t).
__global__ __launch_bounds__(512, 2) void gru_scan_kernel(
    const float* __restrict__ gi0, const float* __restrict__ Wp0,
    const float* __restrict__ s2q0, const float* __restrict__ bh0,
    float* __restrict__ H0, int S0,
    const float* __restrict__ gi1, const float* __restrict__ Wp1,
    const float* __restrict__ s2q1, const float* __restrict__ bh1,
    float* __restrict__ H1, int S1)
{
  const int blk = blockIdx.x;
  const float* gi; const float* Wpad; const float* s2qG; const float* bh; float* Hs; int S;
  if (blk < 32){ gi = gi0 + (size_t)blk*S0*450;  Wpad = Wp0; s2qG = s2q0; bh = bh0;
                 Hs = H0 + (size_t)blk*S0*150;   S = S0; }
  else         { int bb = blk-32;
                 gi = gi1 + (size_t)bb*S1*450;   Wpad = Wp1; s2qG = s2q1; bh = bh1;
                 Hs = H1 + (size_t)bb*S1*150;    S = S1; }
  __shared__ __align__(16) float h[152];
  __shared__ float gh[452];
  const int tid = threadIdx.x;

  R26(DECW) R12(DECW)
  float br = 0.f;
  {
    const float4* wrow4 = (const float4*)(Wpad + (size_t)((tid<450)?tid:0)*152);
    R26(LDW)
    const float4* s2q4 = (const float4*)s2qG;
    const int s2stride = 452; const int s2r = (tid<452) ? tid : 0;
    R12(LDW2)
    if (tid<450) br = bh[tid];
  }
  if (tid < 152) h[tid] = 0.f;
  __syncthreads();
  const float4* h4 = (const float4*)h;

  float g0=0.f,g1=0.f,g2=0.f;
  if (tid < 150){
    g0 = gi[tid]; g1 = gi[150+tid]; g2 = gi[300+tid];
  }
  for (int t=0;t<S;t++){
    float n0=0.f,n1=0.f,n2=0.f;
    if (tid < 150 && t+1 < S){
      const float* gg = gi + (size_t)(t+1)*450;
      n0 = gg[tid]; n1 = gg[150+tid]; n2 = gg[300+tid];
    }
    if (tid < 450){
      float acc0=br, acc1=0.f, acc2=0.f, acc3=0.f;
      R26(FMAW) R12(FMAW)
      gh[tid] = (acc0+acc2)+(acc1+acc3);
    }
    bar_lds();
    if (tid < 150){
      float r = sigm(g0 + gh[tid]);
      float z = sigm(g1 + gh[150+tid]);
      float n = tanh_f(g2 + r*gh[300+tid]);
      float hn = (1.f-z)*n + z*h[tid];
      h[tid] = hn;
      Hs[(size_t)t*150 + tid] = hn;
    }
    bar_lds();
    g0 = n0; g1 = n1; g2 = n2;
  }
}

// ---- match scan: one block per (batch, dir); 512 threads; 3 LDS-only
// barriers/step. 38 weight quads in registers (R14 parked set); extW,
// whq, wl in LDS; in-thread softmax; PsT b128 gate dots; wave_sum64.
// Prologue zeroes Hr[b][0][dir half].
__global__ __launch_bounds__(512, 2) void match_scan_kernel(
    const float* __restrict__ pWp,   // [B,T,152]
    const float* __restrict__ whq,   // [B,J,152]
    const float* __restrict__ giXf,  // [B,T,452]
    const float* __restrict__ giXr,
    const float* __restrict__ Pf,    // [B,J,452]
    const float* __restrict__ Pr,
    const float* __restrict__ WcatF, const float* __restrict__ WcatR, // [600][152]
    const float* __restrict__ s2qF,  const float* __restrict__ s2qR,  // [12][512] f4
    const float* __restrict__ extF,  const float* __restrict__ extR,  // [38][88] f4
    const float* __restrict__ m_bhh, const float* __restrict__ mr_bhh,
    const float* __restrict__ wvec,  // [150]
    float* __restrict__ Hr)          // [B,401,300]
{
  const int b   = blockIdx.x;
  const int dir = blockIdx.y;
  const float* giX  = dir ? giXr : giXf;
  const float* P    = dir ? Pr   : Pf;
  const float* Wcat = dir ? WcatR : WcatF;
  const float* s2qG = dir ? s2qR  : s2qF;
  const float* extG = dir ? extR  : extF;
  const float* bhh  = dir ? mr_bhh : m_bhh;

  __shared__ float4 extW[3344];                // 53,504
  __shared__ __align__(16) float PsT[15000];   // 60,000  [150][100]: k*100+g*32+j
  __shared__ __align__(16) float whqS[JQ*152]; // 18,240
  __shared__ __align__(16) float wrP[760];     //  3,040  [5][152], k-indexed
  __shared__ __align__(16) float h[152];       //    608
  __shared__ float ghsRaw[512];                //  2,048
  __shared__ __align__(16) float pwS[152];     //    608
  __shared__ __align__(16) float wlS[152];     //    608
  __shared__ __align__(16) float sc[32];       //    128  [30..31] = -1e30
                                               // -> 138,784 B
  const int tid  = threadIdx.x;
  const int lane = tid & 63;
  const int wv   = tid >> 6;
  const int er   = (tid < 440) ? (tid % 88) : 0;   // ext row index (k=62+er)
  const int kg   = (tid < 440) ? (tid / 88) : 0;   // ext K-group / wrP segment

  R26(DECW) R12(DECW)
  float br;
  {
    const float4* wrow4 = (const float4*)(Wcat + (size_t)tid*152);
    R26(LDW)
    const float4* s2q4 = (const float4*)s2qG;
    const int s2stride = 512; const int s2r = tid;
    R12(LDW2)
    br = (tid < 450) ? bhh[tid] : 0.f;
  }
  for (int e=tid; e<3344; e+=512) extW[e] = ((const float4*)extG)[e];
  {
    const float4* wq4 = (const float4*)(whq + (size_t)b*JQ*152);
    for (int e=tid; e<JQ*38; e+=512) ((float4*)whqS)[e] = wq4[e];
  }
  for (int e=tid; e<15000; e+=512) PsT[e] = 0.f;
  for (int e=tid; e<760;   e+=512) wrP[e] = 0.f;
  if (tid < 152){
    h[tid] = 0.f;
    wlS[tid] = (tid<150) ? wvec[tid] : 0.f;
  }
  if (tid >= 30 && tid < 32) sc[tid] = -1e30f;
  if (tid < 150) Hr[(size_t)b*T1*300 + dir*150 + tid] = 0.f;  // t=0 row zero
  __syncthreads();
  {
    const float* Pb = P + (size_t)b*JQ*452;
    for (int e=tid; e<JQ*452; e+=512){
      int j = e/452, kk = e - j*452;
      if (kk < 450){
        int g = kk/150, k = kk - g*150;
        PsT[k*100 + g*32 + j] = Pb[e];
      }
    }
  }
  __syncthreads();
  const float4* h4 = (const float4*)h;
  const float4* wrP4 = (const float4*)wrP;

  for (int t=0;t<TLEN;t++){
    const int tt = dir ? (TLEN-1-t) : t;

    // ---- prefetch (issued before phase A; vmcnt waits at use sites) ----
    float gv0=0.f, gv1=0.f, gv2=0.f;
    if (tid < 150){
      const float* g = giX + ((size_t)b*TLEN + tt)*452;
      gv0 = g[tid]; gv1 = g[150+tid]; gv2 = g[300+tid];
    }
    float4 pwv;
    if (tid >= 440 && tid < 478)
      pwv = ((const float4*)(pWp + ((size_t)b*TLEN + tt)*152))[tid-440];

    // A: row dots for rows 0..511 (38 register quads; only h from LDS)
    {
      float acc0=br, acc1=0.f, acc2=0.f, acc3=0.f;
      R26(FMAW) R12(FMAW)
      float v = (acc0+acc2)+(acc1+acc3);
      ghsRaw[tid] = v;
      if (tid >= 450) wrP[tid-450] = v;        // seg0, k=0..61
    }
    // A-ext: Wcat rows 512..599 (Wr outputs k=62..149), 5 K-groups x 88 rows
    if (tid < 440){
      float e0=0.f, e1=0.f;
      #pragma unroll
      for (int j=0;j<8;j++){
        int q = kg*8+j;
        if (q < 38){
          float4 wq = extW[q*88+er]; float4 hq = h4[q];
          e0 = fmaf(hq.x,wq.x,e0); e1 = fmaf(hq.y,wq.y,e1);
          e0 = fmaf(hq.z,wq.z,e0); e1 = fmaf(hq.w,wq.w,e1);
        }
      }
      wrP[kg*152 + 62 + er] = e0+e1;
    }
    if (tid >= 440 && tid < 478) ((float4*)pwS)[tid-440] = pwv;
    bar_lds();                             // b1 (LDS-only)

    // B: scores; base from pwS+wrP, whq/w from LDS; VALU-dominant reduce
    {
      float4 b4 = make_float4(0.f,0.f,0.f,0.f);
      const bool bl = (lane < 38);
      if (bl){
        float4 pw4 = ((const float4*)pwS)[lane];
        float4 s0 = wrP4[lane],        s1 = wrP4[38+lane];
        float4 s2 = wrP4[76+lane],     s3 = wrP4[114+lane];
        float4 s4 = wrP4[152+lane];
        b4.x = pw4.x + s0.x+s1.x+s2.x+s3.x+s4.x;
        b4.y = pw4.y + s0.y+s1.y+s2.y+s3.y+s4.y;
        b4.z = pw4.z + s0.z+s1.z+s2.z+s3.z+s4.z;
        b4.w = pw4.w + s0.w+s1.w+s2.w+s3.w+s4.w;
      }
      #pragma unroll
      for (int jj=0;jj<4;jj++){
        int j = wv + 8*jj;
        float a = 0.f;
        if (j < JQ && bl){
          float4 q4 = ((const float4*)whqS)[j*38 + lane];
          float4 w4 = ((const float4*)wlS)[lane];
          a = w4.x*tanh_f(q4.x+b4.x);
          a = fmaf(w4.y, tanh_f(q4.y+b4.y), a);
          a = fmaf(w4.z, tanh_f(q4.z+b4.z), a);
          a = fmaf(w4.w, tanh_f(q4.w+b4.w), a);
        }
        a = wave_sum64(a);
        if (j < JQ && lane==0) sc[j] = a;
      }
    }
    bar_lds();                             // b2 (LDS-only)

    // C+D+E: in-thread softmax (8 broadcast b128, zero shuffles), then
    // 24 b128 PsT reads for the three gate dots, then GRU combine.
    if (tid < 192){
      const float4* sc4 = (const float4*)sc;
      float4 s0=sc4[0], s1=sc4[1], s2=sc4[2], s3=sc4[3];
      float4 s4=sc4[4], s5=sc4[5], s6=sc4[6], s7=sc4[7];
      float m = fmaxf(fmaxf(fmaxf(q4max(s0),q4max(s1)),fmaxf(q4max(s2),q4max(s3))),
                      fmaxf(fmaxf(q4max(s4),q4max(s5)),fmaxf(q4max(s6),q4max(s7))));
      float4 a0=exp4(s0,m), a1=exp4(s1,m), a2=exp4(s2,m), a3=exp4(s3,m);
      float4 a4=exp4(s4,m), a5=exp4(s5,m), a6=exp4(s6,m), a7=exp4(s7,m);
      float su = ((sum4(a0)+sum4(a1))+(sum4(a2)+sum4(a3)))
               + ((sum4(a4)+sum4(a5))+(sum4(a6)+sum4(a7)));
      float inv = 1.f/su;
      a0=scl4(a0,inv); a1=scl4(a1,inv); a2=scl4(a2,inv); a3=scl4(a3,inv);
      a4=scl4(a4,inv); a5=scl4(a5,inv); a6=scl4(a6,inv); a7=scl4(a7,inv);
      const int k = (tid < 150) ? tid : 0;
      const float4* Pk = (const float4*)(PsT + k*100);
      float accr = gv0, accz = gv1, accn = gv2;
      #define ACC1(acc,P4,A4){ float4 p=P4; \
        acc=fmaf(A4.x,p.x,acc); acc=fmaf(A4.y,p.y,acc); \
        acc=fmaf(A4.z,p.z,acc); acc=fmaf(A4.w,p.w,acc); }
      #define ACCG(acc,g){ ACC1(acc,Pk[g*8+0],a0) ACC1(acc,Pk[g*8+1],a1) \
        ACC1(acc,Pk[g*8+2],a2) ACC1(acc,Pk[g*8+3],a3) ACC1(acc,Pk[g*8+4],a4) \
        ACC1(acc,Pk[g*8+5],a5) ACC1(acc,Pk[g*8+6],a6) ACC1(acc,Pk[g*8+7],a7) }
      ACCG(accr,0) ACCG(accz,1) ACCG(accn,2)
      #undef ACC1
      #undef ACCG
      if (tid < 150){
        float r = sigm(accr + ghsRaw[tid]);
        float z = sigm(accz + ghsRaw[150+tid]);
        float n = tanh_f(accn + r*ghsRaw[300+tid]);
        float hn = (1.f-z)*n + z*h[tid];
        h[tid] = hn;
        Hr[((size_t)b*T1 + (t+1))*300 + dir*150 + tid] = hn;
      }
    }
    bar_lds();                             // b3 (LDS-only; Hr store in flight)
  }
}

// ---- pointer decoder
__global__ __launch_bounds__(512,2) void ptr_scan_kernel(
    const float* __restrict__ enc, const float* __restrict__ Hr,
    const float* __restrict__ W2, const float* __restrict__ pv,
    const float* __restrict__ dWih, const float* __restrict__ dWhh,
    const float* __restrict__ dbih, const float* __restrict__ dbhh,
    void* __restrict__ outv, const int* __restrict__ flag)
{
  const int b = blockIdx.x;
  const int tid = threadIdx.x;
  const int isbf = *flag;
  __shared__ float h[300], hW2[300], sl[T1], al[T1], c[300];
  __shared__ float gis[900], ghs[900];
  __shared__ float vl[300];
  __shared__ float red[8];
  if (tid < 300){ h[tid] = 0.f; vl[tid] = pv[tid]; }
  __syncthreads();
  for (int l=0;l<2;l++){
    if (tid < 300){
      float a0=0.f,a1=0.f;
      for (int i=0;i<300;i+=2){
        a0 += h[i]  *W2[(size_t)i*300+tid];
        a1 += h[i+1]*W2[(size_t)(i+1)*300+tid];
      }
      hW2[tid] = a0+a1;
    }
    __syncthreads();
    {
      const int wv = tid>>6, lane = tid&63;
      for (int t=wv; t<T1; t+=8){
        const float* er = enc + ((size_t)b*T1 + t)*300;
        float acc = 0.f;
        for (int k=lane; k<300; k+=64) acc += vl[k]*tanh_f(er[k] + hW2[k]);
        #pragma unroll
        for (int off=32; off; off>>=1) acc += __shfl_down(acc, off);
        if (lane==0) sl[t] = acc;
      }
    }
    __syncthreads();
    {
      float v = (tid < T1) ? sl[tid] : -1e30f;
      float m = v;
      #pragma unroll
      for (int off=32; off; off>>=1) m = fmaxf(m, __shfl_down(m, off));
      if ((tid&63)==0) red[tid>>6] = m;
      __syncthreads();
      float bm = fmaxf(fmaxf(fmaxf(red[0],red[1]),fmaxf(red[2],red[3])),
                       fmaxf(fmaxf(red[4],red[5]),fmaxf(red[6],red[7])));
      float e = (tid < T1) ? __expf(v-bm) : 0.f;
      float su = e;
      #pragma unroll
      for (int off=32; off; off>>=1) su += __shfl_down(su, off);
      __syncthreads();
      if ((tid&63)==0) red[tid>>6] = su;
      __syncthreads();
      float bs = red[0]+red[1]+red[2]+red[3]+red[4]+red[5]+red[6]+red[7];
      if (tid < T1){
        float a = e/bs;
        al[tid] = a;
        size_t oi = ((size_t)b*2 + l)*T1 + tid;
        if (isbf) ((__hip_bfloat16*)outv)[oi] = __float2bfloat16(a);
        else      ((float*)outv)[oi] = a;
      }
    }
    __syncthreads();
    if (tid < 300){
      float acc = 0.f;
      for (int t=0;t<T1;t++) acc += al[t]*Hr[((size_t)b*T1 + t)*300 + tid];
      c[tid] = acc;
    }
    __syncthreads();
    for (int k=tid; k<900; k+=blockDim.x){
      const float* wi = dWih + (size_t)k*300;
      const float* wh = dWhh + (size_t)k*300;
      float a0 = dbih[k], a1 = dbhh[k];
      for (int i=0;i<300;i++){ a0 += c[i]*wi[i]; a1 += h[i]*wh[i]; }
      gis[k] = a0; ghs[k] = a1;
    }
    __syncthreads();
    if (tid < 300){
      float r = sigm(gis[tid] + ghs[tid]);
      float z = sigm(gis[300+tid] + ghs[300+tid]);
      float n = tanh_f(gis[600+tid] + r*ghs[600+tid]);
      h[tid] = (1.f-z)*n + z*h[tid];
    }
    __syncthreads();
  }
}

} // namespace

extern "C" void kernel_launch(void* const* d_in, const int* in_sizes, int n_in,
                              void* d_out, int out_size, void* d_ws, size_t ws_size,
                              hipStream_t stream)
{
  (void)in_sizes; (void)n_in; (void)out_size; (void)ws_size;
  float* ws = (float*)d_ws;
  int* flag = (int*)d_ws;

  static const int wsz[NW] = {
    67500,67500,450,450,
    67500,67500,450,450,
    22500,22500,22500,150,150,1,
    135000,67500,450,450,
    135000,67500,450,450,
    90000,90000,300,
    270000,270000,900,900
  };
  WDesc desc;
  int cum = 0;
  for (int j=0;j<NW;j++){ desc.src[j] = d_in[3+j]; desc.off[j] = cum; cum += wsz[j]; }
  desc.off[NW] = cum;

  float* WB = ws + 16;
  const float* P_ctx_Wih = WB + desc.off[0];
  const float* P_ctx_Whh = WB + desc.off[1];
  const float* P_ctx_bih = WB + desc.off[2];
  const float* P_ctx_bhh = WB + desc.off[3];
  const float* P_q_Wih   = WB + desc.off[4];
  const float* P_q_Whh   = WB + desc.off[5];
  const float* P_q_bih   = WB + desc.off[6];
  const float* P_q_bhh   = WB + desc.off[7];
  const float* P_Wq      = WB + desc.off[8];
  const float* P_Wp      = WB + desc.off[9];
  const float* P_Wr      = WB + desc.off[10];
  const float* P_w       = WB + desc.off[11];
  const float* P_gb      = WB + desc.off[12];
  const float* P_m_Wih   = WB + desc.off[14];
  const float* P_m_Whh   = WB + desc.off[15];
  const float* P_m_bih   = WB + desc.off[16];
  const float* P_m_bhh   = WB + desc.off[17];
  const float* P_mr_Wih  = WB + desc.off[18];
  const float* P_mr_Whh  = WB + desc.off[19];
  const float* P_mr_bih  = WB + desc.off[20];
  const float* P_mr_bhh  = WB + desc.off[21];
  const float* P_W1      = WB + desc.off[22];
  const float* P_W2      = WB + desc.off[23];
  const float* P_pv      = WB + desc.off[24];
  const float* P_dWih    = WB + desc.off[25];
  const float* P_dWhh    = WB + desc.off[26];
  const float* P_dbih    = WB + desc.off[27];
  const float* P_dbhh    = WB + desc.off[28];

  size_t p = 16 + 1468512;
  float* ctxWhhP = ws + p; p += 68400;    // [450][152]
  float* qWhhP   = ws + p; p += 68400;
  float* s2qCtx  = ws + p; p += 21696;    // [12][452] f4
  float* s2qQ    = ws + p; p += 21696;
  float* WcatF   = ws + p; p += 91200;    // [600][152]
  float* WcatR   = ws + p; p += 91200;
  float* s2qF    = ws + p; p += 24576;    // [12][512] f4
  float* s2qR    = ws + p; p += 24576;
  float* extFg   = ws + p; p += 13376;    // [38][88] f4
  float* extRg   = ws + p; p += 13376;
  // transposed input-projection weights (mode-0 layouts)
  float* ctxWihT = ws + p; p += 67500;    // [150][450]
  float* qWihT   = ws + p; p += 67500;
  float* mXfT    = ws + p; p += 67500;    // m_Wih cols 0..149   -> [150][450]
  float* mXrT    = ws + p; p += 67500;
  float* mQfT    = ws + p; p += 67500;    // m_Wih cols 150..299 -> [150][450]
  float* mQrT    = ws + p; p += 67500;

  float* ctx_gi = ws + p; p += 5760000;   // [B,T,450]; reused as enc later
  float* q_gi   = ws + p; p += 432000;    // [B,J,450]
  float* HpB    = ws + p; p += 1920000;   // [B,T,150]
  float* HqB    = ws + p; p += 144000;    // [B,J,150]
  float* whqB   = ws + p; p += 145920;    // [B,J,152]
  float* PfB    = ws + p; p += 433920;    // [B,J,452]
  float* PrB    = ws + p; p += 433920;
  float* pWpB   = ws + p; p += 1945600;   // [B,T,152]
  float* giXfB  = ws + p; p += 5785600;   // [B,T,452]
  float* giXrB  = ws + p; p += 5785600;
  float* HrB    = ws + p; p += 3849600;   // [B,401,300]
  float* encB   = ctx_gi;                 // [B,401,300]

  // 1) dtype sniff + weight conversion + fused restructure
  sniff_kernel<<<1,256,0,stream>>>((const unsigned int*)d_in[2], flag);
  convert_weights_kernel<<<512,256,0,stream>>>(desc, WB, flag);
  {
    PrepArgs a;
    a.ctxWhh = P_ctx_Whh; a.qWhh = P_q_Whh; a.mWhh = P_m_Whh; a.mrWhh = P_mr_Whh;
    a.Wr = P_Wr; a.ctxWih = P_ctx_Wih; a.qWih = P_q_Wih; a.mWih = P_m_Wih; a.mrWih = P_mr_Wih;
    a.ctxWhhP = ctxWhhP; a.qWhhP = qWhhP; a.s2qCtx = s2qCtx; a.s2qQ = s2qQ;
    a.WcatF = WcatF; a.WcatR = WcatR; a.s2qF = s2qF; a.s2qR = s2qR;
    a.extF = extFg; a.extR = extRg; a.ctxWihT = ctxWihT; a.qWihT = qWihT;
    a.mXfT = mXfT; a.mXrT = mXrT; a.mQfT = mQfT; a.mQrT = mQrT;
    prep_all_kernel<<<2048,256,0,stream>>>(a);
  }

  // 2) embedding + input projections for both encoders (mode-0, 16-row tiles)
  rowproj16_kernel<<<800,512,0,stream>>>(nullptr,(const int*)d_in[0], d_in[2], flag,
                                         ctxWihT, P_ctx_bih, ctx_gi, 12800,450,150,450,450);
  rowproj16_kernel<<<60,512,0,stream>>>(nullptr,(const int*)d_in[1], d_in[2], flag,
                                        qWihT, P_q_bih, q_gi, 960,450,150,450,450);

  // 3) encoder scans
  gru_scan_kernel<<<64,512,0,stream>>>(ctx_gi, ctxWhhP, s2qCtx, P_ctx_bhh, HpB, 400,
                                       q_gi,   qWhhP,   s2qQ,   P_q_bhh,   HqB, 30);

  // 4) Hq/Hp-dependent precomputations (fused triples, single k-loop)
  rowproj16_3_kernel<<<60,512,0,stream>>>(HqB, 960,
      P_Wq, nullptr, whqB, 150, 150, 152,
      mQfT, nullptr, PfB, 450, 450, 452,
      mQrT, nullptr, PrB, 450, 450, 452);
  rowproj16_3_kernel<<<800,512,0,stream>>>(HpB, 12800,
      P_Wp, P_gb, pWpB, 150, 150, 152,
      mXfT, P_m_bih, giXfB, 450, 450, 452,
      mXrT, P_mr_bih, giXrB, 450, 450, 452);

  // 5) match scans (fwd+bwd concurrent; t=0 Hr row zeroed in prologue)
  match_scan_kernel<<<dim3(NBATCH,2),512,0,stream>>>(pWpB, whqB, giXfB, giXrB,
                                                     PfB, PrB, WcatF, WcatR,
                                                     s2qF, s2qR, extFg, extRg,
                                                     P_m_bhh, P_mr_bhh, P_w, HrB);

  // 6) pointer decoder (K=300 -> 320-thread blocks, 94% k-loop util)
  rowproj16_kernel<<<802,320,0,stream>>>(HrB,nullptr,nullptr,nullptr, P_W1, nullptr,
                                         encB, 12832,300,300,300,300);
  ptr_scan_kernel<<<32,512,0,stream>>>(encB, HrB, P_W2, P_pv,
                                       P_dWih, P_dWhh, P_dbih, P_dbhh, d_out, flag);
}